// Round 10
// baseline (249.429 us; speedup 1.0000x reference)
//
#include <hip/hip_runtime.h>
#include <hip/hip_bf16.h>

typedef __attribute__((ext_vector_type(8))) short bf16x8;
typedef __attribute__((ext_vector_type(4))) float f32x4;

#define DEVINL __device__ __forceinline__

constexpr int kB = 8, kL = 512, kDH = 768, kDARC = 512, kDREL = 128, kC = 37;
constexpr int kBL = kB * kL;        // 4096
constexpr int kNP = 1280;           // 512+512+128+128 fused projection cols
constexpr int kNY = kC * kDREL;     // 4736

constexpr long nHB   = (long)kBL * kDH;
constexpr long nWALL = (long)kNP * kDH;
constexpr long nWARC = (long)kDARC * kDARC;
constexpr long nUT   = (long)kC * kDREL * kDREL;
constexpr long nBALL = kNP;

DEVINL short f2b(float f) {
  unsigned u = __float_as_uint(f);
  u += 0x7fffu + ((u >> 16) & 1u);   // RNE
  return (short)(u >> 16);
}
DEVINL float b2f(short s) {
  return __uint_as_float(((unsigned)(unsigned short)s) << 16);
}

// async global->LDS, 16B per lane. LDS dest = wave-uniform base + lane*16 (HW).
DEVINL void gload16(const void* g, void* l) {
  __builtin_amdgcn_global_load_lds(
      (const __attribute__((address_space(1))) void*)g,
      (__attribute__((address_space(3))) void*)l, 16, 0, 0);
}

// LDS-only barrier: orders ds ops across waves WITHOUT draining global stores.
DEVINL void lds_barrier() {
  asm volatile("s_waitcnt lgkmcnt(0)\n\ts_barrier" ::: "memory");
}

// ---------------- convert / pack inputs to bf16 ----------------
__global__ __launch_bounds__(256) void k_convert(
    const float* __restrict__ H, const float* __restrict__ W_ah, const float* __restrict__ b_ah,
    const float* __restrict__ W_ad, const float* __restrict__ b_ad,
    const float* __restrict__ W_arc, const float* __restrict__ W_rh, const float* __restrict__ b_rh,
    const float* __restrict__ W_rd, const float* __restrict__ b_rd, const float* __restrict__ U,
    short* __restrict__ Hb, short* __restrict__ Wall, float* __restrict__ ballf,
    short* __restrict__ Warcb, short* __restrict__ Ut)
{
  const long total = nHB + nWALL + nWARC + nUT + nBALL;
  for (long i = (long)blockIdx.x * blockDim.x + threadIdx.x; i < total;
       i += (long)gridDim.x * blockDim.x) {
    if (i < nHB) {
      Hb[i] = f2b(H[i]);
    } else if (i < nHB + nWALL) {
      long j = i - nHB; int row = (int)(j / kDH); int k = (int)(j - (long)row * kDH);
      float v;
      if (row < 512)       v = W_ah[(long)row * kDH + k];
      else if (row < 1024) v = W_ad[(long)(row - 512) * kDH + k];
      else if (row < 1152) v = W_rh[(long)(row - 1024) * kDH + k];
      else                 v = W_rd[(long)(row - 1152) * kDH + k];
      Wall[j] = f2b(v);
    } else if (i < nHB + nWALL + nWARC) {
      long j = i - nHB - nWALL;
      Warcb[j] = f2b(W_arc[j]);
    } else if (i < nHB + nWALL + nWARC + nUT) {
      long j = i - nHB - nWALL - nWARC;
      int c = (int)(j >> 14); int rem = (int)(j & 16383); int e = rem >> 7; int d = rem & 127;
      Ut[j] = f2b(U[(long)c * 16384 + (long)d * 128 + e]);   // Ut[c][e][d] = U[c][d][e]
    } else {
      int n = (int)(i - nHB - nWALL - nWARC - nUT);
      float v;
      if (n < 512)       v = b_ah[n];
      else if (n < 1024) v = b_ad[n - 512];
      else if (n < 1152) v = b_rh[n - 1024];
      else               v = b_rd[n - 1152];
      ballf[n] = v;
    }
  }
}

// ---------------- 128x128 core: acc += A[128,K] * B[128,K]^T ----------------
DEVINL void gemm128_core(short* As, short* Bs,
                         const short* __restrict__ Ag, long lda,
                         const short* __restrict__ Bg, long ldb,
                         int K, f32x4 acc[4][4])
{
  const int t = threadIdx.x, lane = t & 63, w = t >> 6;
  const int wm = w >> 1, wn = w & 1, fr = lane & 15, hi = lane >> 4;
  const int srow = w * 8 + (lane >> 3);
  const int scol = (lane & 7) * 8;
  const short* Arow = Ag + (long)srow * lda + scol;
  const short* Brow = Bg + (long)srow * ldb + scol;

  for (int k0 = 0; k0 < K; k0 += 64) {
    __syncthreads();
#pragma unroll
    for (int i = 0; i < 4; i++) {
      gload16(Arow + (long)i * 32 * lda + k0, &As[(i * 4 + w) * 512]);
      gload16(Brow + (long)i * 32 * ldb + k0, &Bs[(i * 4 + w) * 512]);
    }
    __syncthreads();   // needs vmcnt(0): global_load_lds completion is vmcnt-tracked
#pragma unroll
    for (int ks = 0; ks < 2; ks++) {
      bf16x8 a[4], b[4];
#pragma unroll
      for (int mf = 0; mf < 4; mf++)
        a[mf] = *(const bf16x8*)&As[(wm * 64 + mf * 16 + fr) * 64 + ks * 32 + hi * 8];
#pragma unroll
      for (int nf = 0; nf < 4; nf++)
        b[nf] = *(const bf16x8*)&Bs[(wn * 64 + nf * 16 + fr) * 64 + ks * 32 + hi * 8];
#pragma unroll
      for (int mf = 0; mf < 4; mf++)
#pragma unroll
        for (int nf = 0; nf < 4; nf++)
          acc[mf][nf] = __builtin_amdgcn_mfma_f32_16x16x32_bf16(a[mf], b[nf], acc[mf][nf], 0, 0, 0);
    }
  }
}

#define ZERO_ACC16 \
  f32x4 acc[4][4]; \
  for (int i = 0; i < 4; i++) for (int j = 0; j < 4; j++) for (int r = 0; r < 4; r++) acc[i][j][r] = 0.f;

// ---------------- projections: Proj = relu(Hb * Wall^T + ballf), bf16 out ----------------
__global__ __launch_bounds__(256) void k_proj(const short* __restrict__ Hb,
    const short* __restrict__ Wall, const float* __restrict__ ballf,
    short* __restrict__ Proj)
{
  __shared__ short As[128 * 64], Bs[128 * 64];
  const int tn = blockIdx.x, tm = blockIdx.y;
  ZERO_ACC16;
  gemm128_core(As, Bs, Hb + (long)tm * 128 * kDH, kDH, Wall + (long)tn * 128 * kDH, kDH, kDH, acc);
  const int lane = threadIdx.x & 63; const int w = threadIdx.x >> 6;
  const int wm = w >> 1, wn = w & 1, fr = lane & 15, hi = lane >> 4;
  for (int mf = 0; mf < 4; mf++) for (int nf = 0; nf < 4; nf++) for (int r = 0; r < 4; r++) {
    int row = tm * 128 + wm * 64 + mf * 16 + hi * 4 + r;
    int col = tn * 128 + wn * 64 + nf * 16 + fr;
    float v = acc[mf][nf][r] + ballf[col];
    v = v > 0.f ? v : 0.f;
    Proj[(long)row * kNP + col] = f2b(v);
  }
}

// ---------------- k_mid: T-tiles + Y-tiles + (rowterm|affine) in one launch ----------------
__global__ __launch_bounds__(256) void k_mid(const short* __restrict__ Proj,
    const short* __restrict__ Warcb, const short* __restrict__ Ut,
    const float* __restrict__ bias_arc, const float* __restrict__ W_rel,
    const float* __restrict__ bias_rel,
    short* __restrict__ T, short* __restrict__ Y,
    float* __restrict__ rowterm, float* __restrict__ affB)
{
  __shared__ short As[128 * 64], Bs[128 * 64];
  const int bx = blockIdx.x;
  const int t = threadIdx.x;

  if (bx < 1312) {
    const short* Ag; const short* Bg;
    long lda, ldb, ldd; int K, tm, tn; short* dst;
    if (bx < 128) {
      tn = bx & 3; tm = bx >> 2;
      Ag = Proj + (long)tm * 128 * kNP + 512; lda = kNP;
      Bg = Warcb + (long)tn * 128 * kDARC;    ldb = kDARC;
      K = kDARC; dst = T; ldd = kDARC;
    } else {
      int i = bx - 128; tn = i % 37; tm = i / 37;
      Ag = Proj + (long)tm * 128 * kNP + 1024; lda = kNP;
      Bg = Ut + (long)tn * 128 * kDREL;        ldb = kDREL;
      K = kDREL; dst = Y; ldd = kNY;
    }
    ZERO_ACC16;
    gemm128_core(As, Bs, Ag, lda, Bg, ldb, K, acc);
    const int lane = t & 63; const int w = t >> 6;
    const int wm = w >> 1, wn = w & 1, fr = lane & 15, hi = lane >> 4;
    for (int mf = 0; mf < 4; mf++) for (int nf = 0; nf < 4; nf++) for (int r = 0; r < 4; r++) {
      int row = tm * 128 + wm * 64 + mf * 16 + hi * 4 + r;
      int col = tn * 128 + wn * 64 + nf * 16 + fr;
      dst[(long)row * ldd + col] = f2b(acc[mf][nf][r]);
    }
  } else {
    __shared__ float h[4][256];
    const int base = (bx - 1312) * 8;
    const int w = t >> 6, lane = t & 63;
    for (int j = 0; j < 2; j++) {
      const int bl = base + w * 2 + j;
      const short* prow = Proj + (long)bl * kNP;
      float s = 0.f;
      bf16x8 hv = *(const bf16x8*)(prow + lane * 8);
#pragma unroll
      for (int i = 0; i < 8; i++) s += b2f(hv[i]) * bias_arc[lane * 8 + i];
      for (int off = 32; off; off >>= 1) s += __shfl_down(s, off, 64);
      if (lane == 0) rowterm[bl] = s;
      if (lane < 32) {
        bf16x8 v = *(const bf16x8*)(prow + 1024 + lane * 8);
        for (int i = 0; i < 8; i++) h[w][lane * 8 + i] = b2f(v[i]);
      }
      __syncthreads();
      if (lane < kC) {
        float sa = bias_rel[lane];
        const float* wr = W_rel + (long)lane * 256;
        for (int k = 0; k < 256; k++) sa += h[w][k] * wr[k];
        affB[(long)bl * kC + lane] = sa;
      }
      __syncthreads();
    }
  }
}

// ---------------- k_out: sarc (128x128 tiles) + srel v3b, 256 threads, dyn LDS ----------------
__global__ __launch_bounds__(256) void k_out(const short* __restrict__ T,
    const short* __restrict__ Proj, const float* __restrict__ rowterm,
    const short* __restrict__ Y, const float* __restrict__ affB,
    float* __restrict__ outArc, float* __restrict__ outRel)
{
  extern __shared__ short sm[];   // 32768 B
  const int t = threadIdx.x;
  const int lane = t & 63, w = t >> 6;
  const int fr = lane & 15, hi = lane >> 4;

  if (blockIdx.x < 128) {
    const int i = blockIdx.x;
    const int b = i >> 4, tm = (i >> 2) & 3, tn = i & 3;
    ZERO_ACC16;
    gemm128_core(sm, sm + 8192,
                 T + ((long)b * kL + tm * 128) * kDARC, kDARC,
                 Proj + ((long)b * kL + tn * 128) * kNP, kNP, kDARC, acc);
    const int wm = w >> 1, wn = w & 1;
    for (int mf = 0; mf < 4; mf++) for (int nf = 0; nf < 4; nf++) for (int r = 0; r < 4; r++) {
      int l = tm * 128 + wm * 64 + mf * 16 + hi * 4 + r;
      int m = tn * 128 + wn * 64 + nf * 16 + fr;
      outArc[((long)b * kL + l) * kL + m] = acc[mf][nf][r] + rowterm[(long)b * kL + l];
    }
  } else {
    const int idx = blockIdx.x - 128;
    const int h = idx & 1;
    const int l0 = ((idx >> 1) & 63) * 8;
    const int b = idx >> 7;
    const int mbase = h * 256;
    short* Bcur = sm;            // 48*136 = 6528 shorts
    short* Bnxt = sm + 6528;

    bf16x8 a[4][4];
    const short* Ab = Proj + ((long)b * kL + mbase + w * 64) * kNP + 1152;
#pragma unroll
    for (int mf = 0; mf < 4; mf++)
#pragma unroll
      for (int ks = 0; ks < 4; ks++)
        a[mf][ks] = *(const bf16x8*)(Ab + (long)(mf * 16 + fr) * kNP + ks * 32 + hi * 8);

    {
      const short* Yrow = Y + ((long)b * kL + l0) * kNY;
#pragma unroll
      for (int p = 0; p < 3; p++) {
        int i2 = p * 256 + t;
        if (i2 < 592)
          *(bf16x8*)&Bcur[(i2 >> 4) * 136 + (i2 & 15) * 8] = *(const bf16x8*)(Yrow + i2 * 8);
      }
    }
    lds_barrier();

    for (int il = 0; il < 8; il++) {
      const long bl = (long)b * kL + l0 + il;

      bf16x8 n0, n1, n2;
      if (il < 7) {
        const short* Yn = Y + (bl + 1) * kNY;
        n0 = *(const bf16x8*)(Yn + t * 8);
        n1 = *(const bf16x8*)(Yn + (long)(256 + t) * 8);
        if (t < 80) n2 = *(const bf16x8*)(Yn + (long)(512 + t) * 8);
      }

      f32x4 acc[4][3];
#pragma unroll
      for (int mf = 0; mf < 4; mf++)
#pragma unroll
        for (int nf = 0; nf < 3; nf++)
          for (int r = 0; r < 4; r++) acc[mf][nf][r] = 0.f;

#pragma unroll
      for (int ks = 0; ks < 4; ks++) {
        bf16x8 bfr[3];
#pragma unroll
        for (int nf = 0; nf < 3; nf++)
          bfr[nf] = *(const bf16x8*)&Bcur[(nf * 16 + fr) * 136 + ks * 32 + hi * 8];
#pragma unroll
        for (int mf = 0; mf < 4; mf++)
#pragma unroll
          for (int nf = 0; nf < 3; nf++)
            acc[mf][nf] = __builtin_amdgcn_mfma_f32_16x16x32_bf16(a[mf][ks], bfr[nf], acc[mf][nf], 0, 0, 0);
      }
      lds_barrier();

      float aff[3];
#pragma unroll
      for (int nf = 0; nf < 3; nf++) {
        int c = nf * 16 + fr;
        aff[nf] = (c < kC) ? affB[bl * kC + c] : 0.f;
      }

      float* scr = (float*)Bcur + w * 592;
#pragma unroll
      for (int mf = 0; mf < 4; mf++) {
#pragma unroll
        for (int nf = 0; nf < 3; nf++) {
          int c = nf * 16 + fr;
          if (c < kC) {
#pragma unroll
            for (int r = 0; r < 4; r++)
              scr[(hi * 4 + r) * kC + c] = acc[mf][nf][r] + aff[nf];
          }
        }
        float* gb = outRel + (bl * kL + mbase + w * 64 + mf * 16) * kC;
#pragma unroll
        for (int p = 0; p < 3; p++) {
          int i4 = p * 64 + lane;
          if (i4 < 148) {
            f32x4 v = *(f32x4*)&scr[i4 * 4];
            *(f32x4*)&gb[i4 * 4] = v;
          }
        }
      }

      if (il < 7) {
        *(bf16x8*)&Bnxt[(t >> 4) * 136 + (t & 15) * 8] = n0;
        {
          int i2 = 256 + t;
          *(bf16x8*)&Bnxt[(i2 >> 4) * 136 + (i2 & 15) * 8] = n1;
        }
        if (t < 80) {
          int i2 = 512 + t;
          *(bf16x8*)&Bnxt[(i2 >> 4) * 136 + (i2 & 15) * 8] = n2;
        }
        lds_barrier();
        short* tmp = Bcur; Bcur = Bnxt; Bnxt = tmp;
      }
    }
  }
}

extern "C" void kernel_launch(void* const* d_in, const int* in_sizes, int n_in,
                              void* d_out, int out_size, void* d_ws, size_t ws_size,
                              hipStream_t stream) {
  const float* H        = (const float*)d_in[0];
  const float* W_ah     = (const float*)d_in[1];
  const float* b_ah     = (const float*)d_in[2];
  const float* W_ad     = (const float*)d_in[3];
  const float* b_ad     = (const float*)d_in[4];
  const float* W_arc    = (const float*)d_in[5];
  const float* bias_arc = (const float*)d_in[6];
  const float* W_rh     = (const float*)d_in[7];
  const float* b_rh     = (const float*)d_in[8];
  const float* W_rd     = (const float*)d_in[9];
  const float* b_rd     = (const float*)d_in[10];
  const float* U_rel    = (const float*)d_in[11];
  const float* W_rel    = (const float*)d_in[12];
  const float* bias_rel = (const float*)d_in[13];

  size_t off = 0;
  auto take = [&](size_t nbytes) -> void* {
    void* p = (char*)d_ws + off;
    off += (nbytes + 255) & ~(size_t)255;
    return p;
  };
  short* Hb      = (short*)take(nHB * 2);
  short* Wall    = (short*)take(nWALL * 2);
  float* ballf   = (float*)take(nBALL * 4);
  short* Warcb   = (short*)take(nWARC * 2);
  short* Ut      = (short*)take(nUT * 2);
  short* Proj    = (short*)take((long)kBL * kNP * 2);
  short* T       = (short*)take((long)kBL * kDARC * 2);
  short* Y       = (short*)take((long)kBL * kNY * 2);
  float* rowterm = (float*)take((long)kBL * 4);
  float* affB    = (float*)take((long)kBL * kC * 4);
  if (off > ws_size) return;

  float* outArc = (float*)d_out;
  float* outRel = outArc + (long)kB * kL * kL;

  k_convert<<<dim3(2048), dim3(256), 0, stream>>>(H, W_ah, b_ah, W_ad, b_ad, W_arc,
                                                  W_rh, b_rh, W_rd, b_rd, U_rel,
                                                  Hb, Wall, ballf, Warcb, Ut);
  k_proj<<<dim3(kNP / 128, kBL / 128), dim3(256), 0, stream>>>(Hb, Wall, ballf, Proj);
  k_mid<<<dim3(1824), dim3(256), 0, stream>>>(Proj, Warcb, Ut, bias_arc, W_rel, bias_rel,
                                              T, Y, rowterm, affB);
  // ===== MEASUREMENT: k_out launched TWICE (idempotent). new_dur - 161 ~= k_out time. =====
  for (int rep = 0; rep < 2; rep++)
    k_out<<<dim3(1152), dim3(256), 32768, stream>>>(T, Proj, rowterm, Y, affB, outArc, outRel);
}

// Round 11
// 180.552 us; speedup vs baseline: 1.3815x; 1.3815x over previous
//
#include <hip/hip_runtime.h>
#include <hip/hip_bf16.h>

typedef __attribute__((ext_vector_type(8))) short bf16x8;
typedef __attribute__((ext_vector_type(4))) float f32x4;

#define DEVINL __device__ __forceinline__

constexpr int kB = 8, kL = 512, kDH = 768, kDARC = 512, kDREL = 128, kC = 37;
constexpr int kBL = kB * kL;        // 4096
constexpr int kNP = 1280;           // 512+512+128+128 fused projection cols
constexpr int kYR = 5032;           // padded Y row: 37 c-blocks x 136 shorts (= LDS image)

constexpr long nHB   = (long)kBL * kDH;
constexpr long nWALL = (long)kNP * kDH;
constexpr long nWARC = (long)kDARC * kDARC;
constexpr long nUT   = (long)kC * kDREL * kDREL;
constexpr long nBALL = kNP;

DEVINL short f2b(float f) {
  unsigned u = __float_as_uint(f);
  u += 0x7fffu + ((u >> 16) & 1u);   // RNE
  return (short)(u >> 16);
}
DEVINL float b2f(short s) {
  return __uint_as_float(((unsigned)(unsigned short)s) << 16);
}

// async global->LDS, 16B per lane. LDS dest = wave-uniform base + lane*16 (HW);
// global source is per-lane.
DEVINL void gload16(const void* g, void* l) {
  __builtin_amdgcn_global_load_lds(
      (const __attribute__((address_space(1))) void*)g,
      (__attribute__((address_space(3))) void*)l, 16, 0, 0);
}

// barrier draining VMEM (covers global_load_lds) + LDS counters
DEVINL void vm_lds_barrier() {
  asm volatile("s_waitcnt vmcnt(0) lgkmcnt(0)\n\ts_barrier" ::: "memory");
}

// ---------------- convert / pack inputs to bf16 ----------------
__global__ __launch_bounds__(256) void k_convert(
    const float* __restrict__ H, const float* __restrict__ W_ah, const float* __restrict__ b_ah,
    const float* __restrict__ W_ad, const float* __restrict__ b_ad,
    const float* __restrict__ W_arc, const float* __restrict__ W_rh, const float* __restrict__ b_rh,
    const float* __restrict__ W_rd, const float* __restrict__ b_rd, const float* __restrict__ U,
    short* __restrict__ Hb, short* __restrict__ Wall, float* __restrict__ ballf,
    short* __restrict__ Warcb, short* __restrict__ Ut)
{
  const long total = nHB + nWALL + nWARC + nUT + nBALL;
  for (long i = (long)blockIdx.x * blockDim.x + threadIdx.x; i < total;
       i += (long)gridDim.x * blockDim.x) {
    if (i < nHB) {
      Hb[i] = f2b(H[i]);
    } else if (i < nHB + nWALL) {
      long j = i - nHB; int row = (int)(j / kDH); int k = (int)(j - (long)row * kDH);
      float v;
      if (row < 512)       v = W_ah[(long)row * kDH + k];
      else if (row < 1024) v = W_ad[(long)(row - 512) * kDH + k];
      else if (row < 1152) v = W_rh[(long)(row - 1024) * kDH + k];
      else                 v = W_rd[(long)(row - 1152) * kDH + k];
      Wall[j] = f2b(v);
    } else if (i < nHB + nWALL + nWARC) {
      long j = i - nHB - nWALL;
      Warcb[j] = f2b(W_arc[j]);
    } else if (i < nHB + nWALL + nWARC + nUT) {
      long j = i - nHB - nWALL - nWARC;
      int c = (int)(j >> 14); int rem = (int)(j & 16383); int e = rem >> 7; int d = rem & 127;
      Ut[j] = f2b(U[(long)c * 16384 + (long)d * 128 + e]);   // Ut[c][e][d] = U[c][d][e]
    } else {
      int n = (int)(i - nHB - nWALL - nWARC - nUT);
      float v;
      if (n < 512)       v = b_ah[n];
      else if (n < 1024) v = b_ad[n - 512];
      else if (n < 1152) v = b_rh[n - 1024];
      else               v = b_rd[n - 1152];
      ballf[n] = v;
    }
  }
}

// ---------------- 128x128 core: acc += A[128,K] * B[128,K]^T ----------------
DEVINL void gemm128_core(short* As, short* Bs,
                         const short* __restrict__ Ag, long lda,
                         const short* __restrict__ Bg, long ldb,
                         int K, f32x4 acc[4][4])
{
  const int t = threadIdx.x, lane = t & 63, w = t >> 6;
  const int wm = w >> 1, wn = w & 1, fr = lane & 15, hi = lane >> 4;
  const int srow = w * 8 + (lane >> 3);
  const int scol = (lane & 7) * 8;
  const short* Arow = Ag + (long)srow * lda + scol;
  const short* Brow = Bg + (long)srow * ldb + scol;

  for (int k0 = 0; k0 < K; k0 += 64) {
    __syncthreads();
#pragma unroll
    for (int i = 0; i < 4; i++) {
      gload16(Arow + (long)i * 32 * lda + k0, &As[(i * 4 + w) * 512]);
      gload16(Brow + (long)i * 32 * ldb + k0, &Bs[(i * 4 + w) * 512]);
    }
    __syncthreads();   // vmcnt(0) drained: global_load_lds completion is vmcnt-tracked
#pragma unroll
    for (int ks = 0; ks < 2; ks++) {
      bf16x8 a[4], b[4];
#pragma unroll
      for (int mf = 0; mf < 4; mf++)
        a[mf] = *(const bf16x8*)&As[(wm * 64 + mf * 16 + fr) * 64 + ks * 32 + hi * 8];
#pragma unroll
      for (int nf = 0; nf < 4; nf++)
        b[nf] = *(const bf16x8*)&Bs[(wn * 64 + nf * 16 + fr) * 64 + ks * 32 + hi * 8];
#pragma unroll
      for (int mf = 0; mf < 4; mf++)
#pragma unroll
        for (int nf = 0; nf < 4; nf++)
          acc[mf][nf] = __builtin_amdgcn_mfma_f32_16x16x32_bf16(a[mf], b[nf], acc[mf][nf], 0, 0, 0);
    }
  }
}

#define ZERO_ACC16 \
  f32x4 acc[4][4]; \
  for (int i = 0; i < 4; i++) for (int j = 0; j < 4; j++) for (int r = 0; r < 4; r++) acc[i][j][r] = 0.f;

// ---------------- projections: Proj = relu(Hb * Wall^T + ballf), bf16 out ----------------
__global__ __launch_bounds__(256) void k_proj(const short* __restrict__ Hb,
    const short* __restrict__ Wall, const float* __restrict__ ballf,
    short* __restrict__ Proj)
{
  __shared__ short As[128 * 64], Bs[128 * 64];
  const int tn = blockIdx.x, tm = blockIdx.y;
  ZERO_ACC16;
  gemm128_core(As, Bs, Hb + (long)tm * 128 * kDH, kDH, Wall + (long)tn * 128 * kDH, kDH, kDH, acc);
  const int lane = threadIdx.x & 63; const int w = threadIdx.x >> 6;
  const int wm = w >> 1, wn = w & 1, fr = lane & 15, hi = lane >> 4;
  for (int mf = 0; mf < 4; mf++) for (int nf = 0; nf < 4; nf++) for (int r = 0; r < 4; r++) {
    int row = tm * 128 + wm * 64 + mf * 16 + hi * 4 + r;
    int col = tn * 128 + wn * 64 + nf * 16 + fr;
    float v = acc[mf][nf][r] + ballf[col];
    v = v > 0.f ? v : 0.f;
    Proj[(long)row * kNP + col] = f2b(v);
  }
}

// ---------------- k_mid: T-tiles + Y-tiles (padded layout) + (rowterm|affine) ----------------
// blocks [0,128): T; [128,1312): Y (tn = c label, 128 e-cols); [1312,1824): small path
__global__ __launch_bounds__(256) void k_mid(const short* __restrict__ Proj,
    const short* __restrict__ Warcb, const short* __restrict__ Ut,
    const float* __restrict__ bias_arc, const float* __restrict__ W_rel,
    const float* __restrict__ bias_rel,
    short* __restrict__ T, short* __restrict__ Ypad,
    float* __restrict__ rowterm, float* __restrict__ affB)
{
  __shared__ short As[128 * 64], Bs[128 * 64];
  const int bx = blockIdx.x;
  const int t = threadIdx.x;

  if (bx < 1312) {
    const short* Ag; const short* Bg;
    long lda, ldb; int K, tm, tn;
    const bool isT = bx < 128;
    if (isT) {
      tn = bx & 3; tm = bx >> 2;
      Ag = Proj + (long)tm * 128 * kNP + 512; lda = kNP;
      Bg = Warcb + (long)tn * 128 * kDARC;    ldb = kDARC;
      K = kDARC;
    } else {
      int i = bx - 128; tn = i % 37; tm = i / 37;
      Ag = Proj + (long)tm * 128 * kNP + 1024; lda = kNP;
      Bg = Ut + (long)tn * 128 * kDREL;        ldb = kDREL;
      K = kDREL;
    }
    ZERO_ACC16;
    gemm128_core(As, Bs, Ag, lda, Bg, ldb, K, acc);
    const int lane = t & 63; const int w = t >> 6;
    const int wm = w >> 1, wn = w & 1, fr = lane & 15, hi = lane >> 4;
    if (isT) {
      for (int mf = 0; mf < 4; mf++) for (int nf = 0; nf < 4; nf++) for (int r = 0; r < 4; r++) {
        int row = tm * 128 + wm * 64 + mf * 16 + hi * 4 + r;
        int col = tn * 128 + wn * 64 + nf * 16 + fr;
        T[(long)row * kDARC + col] = f2b(acc[mf][nf][r]);
      }
    } else {
      // padded Y: element (row, c=tn, e) -> Ypad[row*kYR + tn*136 + e]
      for (int mf = 0; mf < 4; mf++) for (int nf = 0; nf < 4; nf++) for (int r = 0; r < 4; r++) {
        int row = tm * 128 + wm * 64 + mf * 16 + hi * 4 + r;
        int e = wn * 64 + nf * 16 + fr;
        Ypad[(long)row * kYR + tn * 136 + e] = f2b(acc[mf][nf][r]);
      }
    }
  } else {
    __shared__ float h[4][256];
    const int base = (bx - 1312) * 8;
    const int w = t >> 6, lane = t & 63;
    for (int j = 0; j < 2; j++) {
      const int bl = base + w * 2 + j;
      const short* prow = Proj + (long)bl * kNP;
      float s = 0.f;
      bf16x8 hv = *(const bf16x8*)(prow + lane * 8);
#pragma unroll
      for (int i = 0; i < 8; i++) s += b2f(hv[i]) * bias_arc[lane * 8 + i];
      for (int off = 32; off; off >>= 1) s += __shfl_down(s, off, 64);
      if (lane == 0) rowterm[bl] = s;
      if (lane < 32) {
        bf16x8 v = *(const bf16x8*)(prow + 1024 + lane * 8);
        for (int i = 0; i < 8; i++) h[w][lane * 8 + i] = b2f(v[i]);
      }
      __syncthreads();
      if (lane < kC) {
        float sa = bias_rel[lane];
        const float* wr = W_rel + (long)lane * 256;
        for (int k = 0; k < 256; k++) sa += h[w][k] * wr[k];
        affB[(long)bl * kC + lane] = sa;
      }
      __syncthreads();
    }
  }
}

// ---------------- k_sarc: S_arc 128x128 tiles (own launch; backfills srel drain) ----------------
__global__ __launch_bounds__(256) void k_sarc(const short* __restrict__ T,
    const short* __restrict__ Proj, const float* __restrict__ rowterm,
    float* __restrict__ outArc)
{
  __shared__ short As[128 * 64], Bs[128 * 64];
  const int i = blockIdx.x;
  const int b = i >> 4, tm = (i >> 2) & 3, tn = i & 3;
  ZERO_ACC16;
  gemm128_core(As, Bs,
               T + ((long)b * kL + tm * 128) * kDARC, kDARC,
               Proj + ((long)b * kL + tn * 128) * kNP, kNP, kDARC, acc);
  const int lane = threadIdx.x & 63; const int w = threadIdx.x >> 6;
  const int wm = w >> 1, wn = w & 1, fr = lane & 15, hi = lane >> 4;
  for (int mf = 0; mf < 4; mf++) for (int nf = 0; nf < 4; nf++) for (int r = 0; r < 4; r++) {
    int l = tm * 128 + wm * 64 + mf * 16 + hi * 4 + r;
    int m = tn * 128 + wn * 64 + nf * 16 + fr;
    outArc[((long)b * kL + l) * kL + m] = acc[mf][nf][r] + rowterm[(long)b * kL + l];
  }
}

// ---------------- k_srel v7: async gload_lds staging + swapped MFMA + direct stores ----------------
// 1024 blocks, 256 thr: h=idx&1 (m-half), l0=((idx>>1)&63)*8, b=idx>>7.
// Per il: issue 10 gload16 (Ypad row -> Bnxt), 12 ds_read_b128 + 48 MFMA on Bcur,
// ~13 direct f32x4 stores, one vm_lds_barrier.
__global__ __launch_bounds__(256) void k_srel(const short* __restrict__ Proj,
    const short* __restrict__ Ypad, const float* __restrict__ affB,
    float* __restrict__ outRel)
{
  __shared__ short Bbuf[2][48 * 136];   // 2 x 13056 B; rows 37..47 uninit (discarded cols)
  const int t = threadIdx.x;
  const int lane = t & 63, w = t >> 6;
  const int fr = lane & 15, hi = lane >> 4;
  const int idx = blockIdx.x;
  const int h = idx & 1;
  const int l0 = ((idx >> 1) & 63) * 8;
  const int b = idx >> 7;
  const int mbase = h * 256;

  // Hrd fragments (il-invariant): rows mbase + w*64 + mf*16 + fr, Proj cols 1152+
  bf16x8 a[4][4];
  const short* Ab = Proj + ((long)b * kL + mbase + w * 64) * kNP + 1152;
#pragma unroll
  for (int mf = 0; mf < 4; mf++)
#pragma unroll
    for (int ks = 0; ks < 4; ks++)
      a[mf][ks] = *(const bf16x8*)(Ab + (long)(mf * 16 + fr) * kNP + ks * 32 + hi * 8);

  // staging helper: Ypad row (10064 B) -> LDS buf, 10 gload16 instrs across 4 waves
  const char* Ybase = (const char*)(Ypad + (long)(b * kL + l0) * kYR);

  // prologue: stage il=0 into Bbuf[0]
#pragma unroll
  for (int i = 0; i < 3; i++) {
    int ii = w + i * 4;
    if (ii < 10) {
      int off = ii * 1024;
      if (off + lane * 16 < 10064)
        gload16(Ybase + off + lane * 16, (char*)Bbuf[0] + off);
    }
  }
  vm_lds_barrier();

  int cur = 0;
  for (int il = 0; il < 8; il++) {
    const long bl = (long)b * kL + l0 + il;

    // T3-lite: issue next-l staging into the other buffer (flies across MFMA+stores)
    if (il < 7) {
      const char* Yn = Ybase + (long)(il + 1) * kYR * 2;
#pragma unroll
      for (int i = 0; i < 3; i++) {
        int ii = w + i * 4;
        if (ii < 10) {
          int off = ii * 1024;
          if (off + lane * 16 < 10064)
            gload16(Yn + off + lane * 16, (char*)Bbuf[cur ^ 1] + off);
        }
      }
    }

    // SWAPPED MFMA: acc[cf][mf]; row-dim = c (Y rows, hi*4+r), col-dim = m (Hrd rows, fr)
    f32x4 acc[3][4];
#pragma unroll
    for (int cf = 0; cf < 3; cf++)
#pragma unroll
      for (int mf = 0; mf < 4; mf++)
        for (int r = 0; r < 4; r++) acc[cf][mf][r] = 0.f;

#pragma unroll
    for (int ks = 0; ks < 4; ks++) {
      bf16x8 yfr[3];
#pragma unroll
      for (int cf = 0; cf < 3; cf++)
        yfr[cf] = *(const bf16x8*)&Bbuf[cur][(cf * 16 + fr) * 136 + ks * 32 + hi * 8];
#pragma unroll
      for (int cf = 0; cf < 3; cf++)
#pragma unroll
        for (int mf = 0; mf < 4; mf++)
          acc[cf][mf] = __builtin_amdgcn_mfma_f32_16x16x32_bf16(yfr[cf], a[mf][ks], acc[cf][mf], 0, 0, 0);
    }

    // affine (c = cf*16 + hi*4 + r)
    const float* afb = affB + bl * kC;
    f32x4 aff0 = *(const f32x4*)&afb[hi * 4];
    f32x4 aff1 = *(const f32x4*)&afb[16 + hi * 4];

    // direct stores: lane (fr,hi) owns m = mbase+w*64+mf*16+fr, c = cf*16+hi*4..+3
    for (int mf = 0; mf < 4; mf++) {
      float* gb = outRel + (bl * kL + mbase + w * 64 + mf * 16 + fr) * kC;
      *(f32x4*)&gb[hi * 4] = acc[0][mf] + aff0;
      *(f32x4*)&gb[16 + hi * 4] = acc[1][mf] + aff1;
      if (hi == 0) {
        f32x4 v2 = acc[2][mf] + *(const f32x4*)&afb[32];
        *(f32x4*)&gb[32] = v2;
      } else if (hi == 1) {
        gb[36] = acc[2][mf][0] + afb[36];
      }
    }

    // single barrier: staging for il+1 complete (vmcnt) + all waves done reading Bcur (lgkm)
    if (il < 7) {
      vm_lds_barrier();
      cur ^= 1;
    }
  }
}

extern "C" void kernel_launch(void* const* d_in, const int* in_sizes, int n_in,
                              void* d_out, int out_size, void* d_ws, size_t ws_size,
                              hipStream_t stream) {
  const float* H        = (const float*)d_in[0];
  const float* W_ah     = (const float*)d_in[1];
  const float* b_ah     = (const float*)d_in[2];
  const float* W_ad     = (const float*)d_in[3];
  const float* b_ad     = (const float*)d_in[4];
  const float* W_arc    = (const float*)d_in[5];
  const float* bias_arc = (const float*)d_in[6];
  const float* W_rh     = (const float*)d_in[7];
  const float* b_rh     = (const float*)d_in[8];
  const float* W_rd     = (const float*)d_in[9];
  const float* b_rd     = (const float*)d_in[10];
  const float* U_rel    = (const float*)d_in[11];
  const float* W_rel    = (const float*)d_in[12];
  const float* bias_rel = (const float*)d_in[13];

  size_t off = 0;
  auto take = [&](size_t nbytes) -> void* {
    void* p = (char*)d_ws + off;
    off += (nbytes + 255) & ~(size_t)255;
    return p;
  };
  short* Hb      = (short*)take(nHB * 2);
  short* Wall    = (short*)take(nWALL * 2);
  float* ballf   = (float*)take(nBALL * 4);
  short* Warcb   = (short*)take(nWARC * 2);
  short* Ut      = (short*)take(nUT * 2);
  short* Proj    = (short*)take((long)kBL * kNP * 2);
  short* T       = (short*)take((long)kBL * kDARC * 2);
  short* Ypad    = (short*)take((long)kBL * kYR * 2);
  float* rowterm = (float*)take((long)kBL * 4);
  float* affB    = (float*)take((long)kBL * kC * 4);
  if (off > ws_size) return;

  float* outArc = (float*)d_out;
  float* outRel = outArc + (long)kB * kL * kL;

  k_convert<<<dim3(2048), dim3(256), 0, stream>>>(H, W_ah, b_ah, W_ad, b_ad, W_arc,
                                                  W_rh, b_rh, W_rd, b_rd, U_rel,
                                                  Hb, Wall, ballf, Warcb, Ut);
  k_proj<<<dim3(kNP / 128, kBL / 128), dim3(256), 0, stream>>>(Hb, Wall, ballf, Proj);
  k_mid<<<dim3(1824), dim3(256), 0, stream>>>(Proj, Warcb, Ut, bias_arc, W_rel, bias_rel,
                                              T, Ypad, rowterm, affB);
  k_srel<<<dim3(1024), dim3(256), 0, stream>>>(Proj, Ypad, affB, outRel);
  k_sarc<<<dim3(128), dim3(256), 0, stream>>>(T, Proj, rowterm, outArc);
}

// Round 12
// 170.958 us; speedup vs baseline: 1.4590x; 1.0561x over previous
//
#include <hip/hip_runtime.h>
#include <hip/hip_bf16.h>

typedef __attribute__((ext_vector_type(8))) short bf16x8;
typedef __attribute__((ext_vector_type(4))) float f32x4;

#define DEVINL __device__ __forceinline__

constexpr int kB = 8, kL = 512, kDH = 768, kDARC = 512, kDREL = 128, kC = 37;
constexpr int kBL = kB * kL;        // 4096
constexpr int kNP = 1280;           // 512+512+128+128 fused projection cols
constexpr int kNY = kC * kDREL;     // 4736

constexpr long nHB   = (long)kBL * kDH;
constexpr long nWALL = (long)kNP * kDH;
constexpr long nWARC = (long)kDARC * kDARC;
constexpr long nUT   = (long)kC * kDREL * kDREL;
constexpr long nBALL = kNP;

DEVINL short f2b(float f) {
  unsigned u = __float_as_uint(f);
  u += 0x7fffu + ((u >> 16) & 1u);   // RNE
  return (short)(u >> 16);
}
DEVINL float b2f(short s) {
  return __uint_as_float(((unsigned)(unsigned short)s) << 16);
}

// async global->LDS, 16B per lane. LDS dest = wave-uniform base + lane*16 (HW).
DEVINL void gload16(const void* g, void* l) {
  __builtin_amdgcn_global_load_lds(
      (const __attribute__((address_space(1))) void*)g,
      (__attribute__((address_space(3))) void*)l, 16, 0, 0);
}

// LDS-only barrier: orders ds ops across waves WITHOUT draining global stores.
DEVINL void lds_barrier() {
  asm volatile("s_waitcnt lgkmcnt(0)\n\ts_barrier" ::: "memory");
}

// ---------------- convert / pack inputs to bf16 ----------------
__global__ __launch_bounds__(256) void k_convert(
    const float* __restrict__ H, const float* __restrict__ W_ah, const float* __restrict__ b_ah,
    const float* __restrict__ W_ad, const float* __restrict__ b_ad,
    const float* __restrict__ W_arc, const float* __restrict__ W_rh, const float* __restrict__ b_rh,
    const float* __restrict__ W_rd, const float* __restrict__ b_rd, const float* __restrict__ U,
    short* __restrict__ Hb, short* __restrict__ Wall, float* __restrict__ ballf,
    short* __restrict__ Warcb, short* __restrict__ Ut)
{
  const long total = nHB + nWALL + nWARC + nUT + nBALL;
  for (long i = (long)blockIdx.x * blockDim.x + threadIdx.x; i < total;
       i += (long)gridDim.x * blockDim.x) {
    if (i < nHB) {
      Hb[i] = f2b(H[i]);
    } else if (i < nHB + nWALL) {
      long j = i - nHB; int row = (int)(j / kDH); int k = (int)(j - (long)row * kDH);
      float v;
      if (row < 512)       v = W_ah[(long)row * kDH + k];
      else if (row < 1024) v = W_ad[(long)(row - 512) * kDH + k];
      else if (row < 1152) v = W_rh[(long)(row - 1024) * kDH + k];
      else                 v = W_rd[(long)(row - 1152) * kDH + k];
      Wall[j] = f2b(v);
    } else if (i < nHB + nWALL + nWARC) {
      long j = i - nHB - nWALL;
      Warcb[j] = f2b(W_arc[j]);
    } else if (i < nHB + nWALL + nWARC + nUT) {
      long j = i - nHB - nWALL - nWARC;
      int c = (int)(j >> 14); int rem = (int)(j & 16383); int e = rem >> 7; int d = rem & 127;
      Ut[j] = f2b(U[(long)c * 16384 + (long)d * 128 + e]);   // Ut[c][e][d] = U[c][d][e]
    } else {
      int n = (int)(i - nHB - nWALL - nWARC - nUT);
      float v;
      if (n < 512)       v = b_ah[n];
      else if (n < 1024) v = b_ad[n - 512];
      else if (n < 1152) v = b_rh[n - 1024];
      else               v = b_rd[n - 1152];
      ballf[n] = v;
    }
  }
}

// ---------------- 128x128 core: acc += A[128,K] * B[128,K]^T ----------------
DEVINL void gemm128_core(short* As, short* Bs,
                         const short* __restrict__ Ag, long lda,
                         const short* __restrict__ Bg, long ldb,
                         int K, f32x4 acc[4][4])
{
  const int t = threadIdx.x, lane = t & 63, w = t >> 6;
  const int wm = w >> 1, wn = w & 1, fr = lane & 15, hi = lane >> 4;
  const int srow = w * 8 + (lane >> 3);
  const int scol = (lane & 7) * 8;
  const short* Arow = Ag + (long)srow * lda + scol;
  const short* Brow = Bg + (long)srow * ldb + scol;

  for (int k0 = 0; k0 < K; k0 += 64) {
    __syncthreads();
#pragma unroll
    for (int i = 0; i < 4; i++) {
      gload16(Arow + (long)i * 32 * lda + k0, &As[(i * 4 + w) * 512]);
      gload16(Brow + (long)i * 32 * ldb + k0, &Bs[(i * 4 + w) * 512]);
    }
    __syncthreads();   // vmcnt(0) drained: global_load_lds completion is vmcnt-tracked
#pragma unroll
    for (int ks = 0; ks < 2; ks++) {
      bf16x8 a[4], b[4];
#pragma unroll
      for (int mf = 0; mf < 4; mf++)
        a[mf] = *(const bf16x8*)&As[(wm * 64 + mf * 16 + fr) * 64 + ks * 32 + hi * 8];
#pragma unroll
      for (int nf = 0; nf < 4; nf++)
        b[nf] = *(const bf16x8*)&Bs[(wn * 64 + nf * 16 + fr) * 64 + ks * 32 + hi * 8];
#pragma unroll
      for (int mf = 0; mf < 4; mf++)
#pragma unroll
        for (int nf = 0; nf < 4; nf++)
          acc[mf][nf] = __builtin_amdgcn_mfma_f32_16x16x32_bf16(a[mf], b[nf], acc[mf][nf], 0, 0, 0);
    }
  }
}

#define ZERO_ACC16 \
  f32x4 acc[4][4]; \
  for (int i = 0; i < 4; i++) for (int j = 0; j < 4; j++) for (int r = 0; r < 4; r++) acc[i][j][r] = 0.f;

// ---------------- projections: Proj = relu(Hb * Wall^T + ballf), bf16 out ----------------
__global__ __launch_bounds__(256) void k_proj(const short* __restrict__ Hb,
    const short* __restrict__ Wall, const float* __restrict__ ballf,
    short* __restrict__ Proj)
{
  __shared__ short As[128 * 64], Bs[128 * 64];
  const int tn = blockIdx.x, tm = blockIdx.y;
  ZERO_ACC16;
  gemm128_core(As, Bs, Hb + (long)tm * 128 * kDH, kDH, Wall + (long)tn * 128 * kDH, kDH, kDH, acc);
  const int lane = threadIdx.x & 63; const int w = threadIdx.x >> 6;
  const int wm = w >> 1, wn = w & 1, fr = lane & 15, hi = lane >> 4;
  for (int mf = 0; mf < 4; mf++) for (int nf = 0; nf < 4; nf++) for (int r = 0; r < 4; r++) {
    int row = tm * 128 + wm * 64 + mf * 16 + hi * 4 + r;
    int col = tn * 128 + wn * 64 + nf * 16 + fr;
    float v = acc[mf][nf][r] + ballf[col];
    v = v > 0.f ? v : 0.f;
    Proj[(long)row * kNP + col] = f2b(v);
  }
}

// ---------------- k_mid: T-tiles + Y-tiles + (rowterm|affine) in one launch ----------------
__global__ __launch_bounds__(256) void k_mid(const short* __restrict__ Proj,
    const short* __restrict__ Warcb, const short* __restrict__ Ut,
    const float* __restrict__ bias_arc, const float* __restrict__ W_rel,
    const float* __restrict__ bias_rel,
    short* __restrict__ T, short* __restrict__ Y,
    float* __restrict__ rowterm, float* __restrict__ affB)
{
  __shared__ short As[128 * 64], Bs[128 * 64];
  const int bx = blockIdx.x;
  const int t = threadIdx.x;

  if (bx < 1312) {
    const short* Ag; const short* Bg;
    long lda, ldb, ldd; int K, tm, tn; short* dst;
    if (bx < 128) {
      tn = bx & 3; tm = bx >> 2;
      Ag = Proj + (long)tm * 128 * kNP + 512; lda = kNP;
      Bg = Warcb + (long)tn * 128 * kDARC;    ldb = kDARC;
      K = kDARC; dst = T; ldd = kDARC;
    } else {
      int i = bx - 128; tn = i % 37; tm = i / 37;
      Ag = Proj + (long)tm * 128 * kNP + 1024; lda = kNP;
      Bg = Ut + (long)tn * 128 * kDREL;        ldb = kDREL;
      K = kDREL; dst = Y; ldd = kNY;
    }
    ZERO_ACC16;
    gemm128_core(As, Bs, Ag, lda, Bg, ldb, K, acc);
    const int lane = t & 63; const int w = t >> 6;
    const int wm = w >> 1, wn = w & 1, fr = lane & 15, hi = lane >> 4;
    for (int mf = 0; mf < 4; mf++) for (int nf = 0; nf < 4; nf++) for (int r = 0; r < 4; r++) {
      int row = tm * 128 + wm * 64 + mf * 16 + hi * 4 + r;
      int col = tn * 128 + wn * 64 + nf * 16 + fr;
      dst[(long)row * ldd + col] = f2b(acc[mf][nf][r]);
    }
  } else {
    __shared__ float h[4][256];
    const int base = (bx - 1312) * 8;
    const int w = t >> 6, lane = t & 63;
    for (int j = 0; j < 2; j++) {
      const int bl = base + w * 2 + j;
      const short* prow = Proj + (long)bl * kNP;
      float s = 0.f;
      bf16x8 hv = *(const bf16x8*)(prow + lane * 8);
#pragma unroll
      for (int i = 0; i < 8; i++) s += b2f(hv[i]) * bias_arc[lane * 8 + i];
      for (int off = 32; off; off >>= 1) s += __shfl_down(s, off, 64);
      if (lane == 0) rowterm[bl] = s;
      if (lane < 32) {
        bf16x8 v = *(const bf16x8*)(prow + 1024 + lane * 8);
        for (int i = 0; i < 8; i++) h[w][lane * 8 + i] = b2f(v[i]);
      }
      __syncthreads();
      if (lane < kC) {
        float sa = bias_rel[lane];
        const float* wr = W_rel + (long)lane * 256;
        for (int k = 0; k < 256; k++) sa += h[w][k] * wr[k];
        affB[(long)bl * kC + lane] = sa;
      }
      __syncthreads();
    }
  }
}

// ---------------- k_out: sarc (128x128 tiles) + srel v8, 256 threads, dyn LDS ----------------
// blocks [0,128): S_arc: b=i>>4, tm=(i>>2)&3, tn=i&3
// blocks [128,2176): srel v8: idx=i-128: h=idx&3 (m-quarter, 128 rows),
//                    l0=((idx>>2)&63)*8, b=idx>>8. VGPR<=128 -> 16 waves/CU.
__global__ __launch_bounds__(256, 4) void k_out(const short* __restrict__ T,
    const short* __restrict__ Proj, const float* __restrict__ rowterm,
    const short* __restrict__ Y, const float* __restrict__ affB,
    float* __restrict__ outArc, float* __restrict__ outRel)
{
  extern __shared__ short sm[];   // 32768 B
  const int t = threadIdx.x;
  const int lane = t & 63, w = t >> 6;
  const int fr = lane & 15, hi = lane >> 4;

  if (blockIdx.x < 128) {
    const int i = blockIdx.x;
    const int b = i >> 4, tm = (i >> 2) & 3, tn = i & 3;
    ZERO_ACC16;
    gemm128_core(sm, sm + 8192,
                 T + ((long)b * kL + tm * 128) * kDARC, kDARC,
                 Proj + ((long)b * kL + tn * 128) * kNP, kNP, kDARC, acc);
    const int wm = w >> 1, wn = w & 1;
    for (int mf = 0; mf < 4; mf++) for (int nf = 0; nf < 4; nf++) for (int r = 0; r < 4; r++) {
      int l = tm * 128 + wm * 64 + mf * 16 + hi * 4 + r;
      int m = tn * 128 + wn * 64 + nf * 16 + fr;
      outArc[((long)b * kL + l) * kL + m] = acc[mf][nf][r] + rowterm[(long)b * kL + l];
    }
  } else {
    // ---- srel v8: 128 m-rows/block (half VGPR), R7 epilogue unchanged ----
    const int idx = blockIdx.x - 128;
    const int h = idx & 3;
    const int l0 = ((idx >> 2) & 63) * 8;
    const int b = idx >> 8;
    const int mbase = h * 128;
    short* Bcur = sm;            // 48*136 = 6528 shorts = 13056 B
    short* Bnxt = sm + 6528;

    // A fragments: Hrd rows b*512 + mbase + w*32 + mf*16 + fr (Proj cols 1152+)
    bf16x8 a[2][4];
    const short* Ab = Proj + ((long)b * kL + mbase + w * 32) * kNP + 1152;
#pragma unroll
    for (int mf = 0; mf < 2; mf++)
#pragma unroll
      for (int ks = 0; ks < 4; ks++)
        a[mf][ks] = *(const bf16x8*)(Ab + (long)(mf * 16 + fr) * kNP + ks * 32 + hi * 8);

    // prologue: stage Y[l0] into Bcur (592 bf16x8 chunks over 256 threads)
    {
      const short* Yrow = Y + ((long)b * kL + l0) * kNY;
#pragma unroll
      for (int p = 0; p < 3; p++) {
        int i2 = p * 256 + t;
        if (i2 < 592)
          *(bf16x8*)&Bcur[(i2 >> 4) * 136 + (i2 & 15) * 8] = *(const bf16x8*)(Yrow + i2 * 8);
      }
    }
    lds_barrier();

    for (int il = 0; il < 8; il++) {
      const long bl = (long)b * kL + l0 + il;

      // T14: issue next-l global loads before compute
      bf16x8 n0, n1, n2;
      if (il < 7) {
        const short* Yn = Y + (bl + 1) * kNY;
        n0 = *(const bf16x8*)(Yn + t * 8);
        n1 = *(const bf16x8*)(Yn + (long)(256 + t) * 8);
        if (t < 80) n2 = *(const bf16x8*)(Yn + (long)(512 + t) * 8);
      }

      f32x4 acc[2][3];
#pragma unroll
      for (int mf = 0; mf < 2; mf++)
#pragma unroll
        for (int nf = 0; nf < 3; nf++)
          for (int r = 0; r < 4; r++) acc[mf][nf][r] = 0.f;

#pragma unroll
      for (int ks = 0; ks < 4; ks++) {
        bf16x8 bfr[3];
#pragma unroll
        for (int nf = 0; nf < 3; nf++)
          bfr[nf] = *(const bf16x8*)&Bcur[(nf * 16 + fr) * 136 + ks * 32 + hi * 8];
#pragma unroll
        for (int mf = 0; mf < 2; mf++)
#pragma unroll
          for (int nf = 0; nf < 3; nf++)
            acc[mf][nf] = __builtin_amdgcn_mfma_f32_16x16x32_bf16(a[mf][ks], bfr[nf], acc[mf][nf], 0, 0, 0);
      }
      lds_barrier();   // all waves done reading Bcur; its space becomes scratch

      float aff[3];
#pragma unroll
      for (int nf = 0; nf < 3; nf++) {
        int c = nf * 16 + fr;
        aff[nf] = (c < kC) ? affB[bl * kC + c] : 0.f;
      }

      // epilogue (R7-proven): per (wave, mf) transpose 16x37 via per-wave scratch
      // in Bcur, then 148 dwordx4 coalesced stores.
      float* scr = (float*)Bcur + w * 592;
#pragma unroll
      for (int mf = 0; mf < 2; mf++) {
#pragma unroll
        for (int nf = 0; nf < 3; nf++) {
          int c = nf * 16 + fr;
          if (c < kC) {
#pragma unroll
            for (int r = 0; r < 4; r++)
              scr[(hi * 4 + r) * kC + c] = acc[mf][nf][r] + aff[nf];
          }
        }
        float* gb = outRel + (bl * kL + mbase + w * 32 + mf * 16) * kC;
#pragma unroll
        for (int p = 0; p < 3; p++) {
          int i4 = p * 64 + lane;
          if (i4 < 148) {
            f32x4 v = *(f32x4*)&scr[i4 * 4];
            *(f32x4*)&gb[i4 * 4] = v;
          }
        }
      }

      if (il < 7) {
        *(bf16x8*)&Bnxt[(t >> 4) * 136 + (t & 15) * 8] = n0;
        {
          int i2 = 256 + t;
          *(bf16x8*)&Bnxt[(i2 >> 4) * 136 + (i2 & 15) * 8] = n1;
        }
        if (t < 80) {
          int i2 = 512 + t;
          *(bf16x8*)&Bnxt[(i2 >> 4) * 136 + (i2 & 15) * 8] = n2;
        }
        lds_barrier();   // publish Bnxt; epilogue stores stay in flight
        short* tmp = Bcur; Bcur = Bnxt; Bnxt = tmp;
      }
    }
  }
}

extern "C" void kernel_launch(void* const* d_in, const int* in_sizes, int n_in,
                              void* d_out, int out_size, void* d_ws, size_t ws_size,
                              hipStream_t stream) {
  const float* H        = (const float*)d_in[0];
  const float* W_ah     = (const float*)d_in[1];
  const float* b_ah     = (const float*)d_in[2];
  const float* W_ad     = (const float*)d_in[3];
  const float* b_ad     = (const float*)d_in[4];
  const float* W_arc    = (const float*)d_in[5];
  const float* bias_arc = (const float*)d_in[6];
  const float* W_rh     = (const float*)d_in[7];
  const float* b_rh     = (const float*)d_in[8];
  const float* W_rd     = (const float*)d_in[9];
  const float* b_rd     = (const float*)d_in[10];
  const float* U_rel    = (const float*)d_in[11];
  const float* W_rel    = (const float*)d_in[12];
  const float* bias_rel = (const float*)d_in[13];

  size_t off = 0;
  auto take = [&](size_t nbytes) -> void* {
    void* p = (char*)d_ws + off;
    off += (nbytes + 255) & ~(size_t)255;
    return p;
  };
  short* Hb      = (short*)take(nHB * 2);
  short* Wall    = (short*)take(nWALL * 2);
  float* ballf   = (float*)take(nBALL * 4);
  short* Warcb   = (short*)take(nWARC * 2);
  short* Ut      = (short*)take(nUT * 2);
  short* Proj    = (short*)take((long)kBL * kNP * 2);
  short* T       = (short*)take((long)kBL * kDARC * 2);
  short* Y       = (short*)take((long)kBL * kNY * 2);
  float* rowterm = (float*)take((long)kBL * 4);
  float* affB    = (float*)take((long)kBL * kC * 4);
  if (off > ws_size) return;

  float* outArc = (float*)d_out;
  float* outRel = outArc + (long)kB * kL * kL;

  k_convert<<<dim3(2048), dim3(256), 0, stream>>>(H, W_ah, b_ah, W_ad, b_ad, W_arc,
                                                  W_rh, b_rh, W_rd, b_rd, U_rel,
                                                  Hb, Wall, ballf, Warcb, Ut);
  k_proj<<<dim3(kNP / 128, kBL / 128), dim3(256), 0, stream>>>(Hb, Wall, ballf, Proj);
  k_mid<<<dim3(1824), dim3(256), 0, stream>>>(Proj, Warcb, Ut, bias_arc, W_rel, bias_rel,
                                              T, Y, rowterm, affB);
  k_out<<<dim3(128 + 2048), dim3(256), 32768, stream>>>(T, Proj, rowterm, Y, affB, outArc, outRel);
}

// Round 13
// 153.041 us; speedup vs baseline: 1.6298x; 1.1171x over previous
//
#include <hip/hip_runtime.h>
#include <hip/hip_bf16.h>

typedef __attribute__((ext_vector_type(8))) short bf16x8;
typedef __attribute__((ext_vector_type(4))) float f32x4;
typedef __attribute__((ext_vector_type(4))) short s16x4;

#define DEVINL __device__ __forceinline__

constexpr int kB = 8, kL = 512, kDH = 768, kDARC = 512, kDREL = 128, kC = 37;
constexpr int kBL = kB * kL;        // 4096
constexpr int kNP = 1280;           // 512+512+128+128 fused projection cols
constexpr int kNY = kC * kDREL;     // 4736

constexpr long nHB   = (long)kBL * kDH;
constexpr long nWALL = (long)kNP * kDH;
constexpr long nWARC = (long)kDARC * kDARC;
constexpr long nUT   = (long)kC * kDREL * kDREL;
constexpr long nBALL = kNP;

constexpr long nHv4 = nHB / 4;       // 786432
constexpr long nWv4 = nWALL / 4;     // 245760
constexpr long nAv4 = nWARC / 4;     //  65536
constexpr long nBv4 = nBALL / 4;     //    320
constexpr long totV4 = nHv4 + nWv4 + nAv4 + nBv4;

DEVINL short f2b(float f) {
  unsigned u = __float_as_uint(f);
  u += 0x7fffu + ((u >> 16) & 1u);   // RNE
  return (short)(u >> 16);
}
DEVINL float b2f(short s) {
  return __uint_as_float(((unsigned)(unsigned short)s) << 16);
}

// async global->LDS, 16B per lane. LDS dest = wave-uniform base + lane*16 (HW).
DEVINL void gload16(const void* g, void* l) {
  __builtin_amdgcn_global_load_lds(
      (const __attribute__((address_space(1))) void*)g,
      (__attribute__((address_space(3))) void*)l, 16, 0, 0);
}

// LDS-only barrier: orders ds ops across waves WITHOUT draining global stores.
DEVINL void lds_barrier() {
  asm volatile("s_waitcnt lgkmcnt(0)\n\ts_barrier" ::: "memory");
}

// ---------------- convert v2: vectorized streams + LDS-transposed Ut ----------------
// blocks [0,2048): grid-stride float4->short4 over {H, Wall=concat(W_ah|W_ad|W_rh|W_rd),
//                  W_arc, ballf(f32 copy)} — all identity layouts.
// blocks [2048,2196): Ut 64x64 transpose tiles (bt = c*4 + tile), coalesced both sides.
__global__ __launch_bounds__(256) void k_convert(
    const float* __restrict__ H, const float* __restrict__ W_ah, const float* __restrict__ b_ah,
    const float* __restrict__ W_ad, const float* __restrict__ b_ad,
    const float* __restrict__ W_arc, const float* __restrict__ W_rh, const float* __restrict__ b_rh,
    const float* __restrict__ W_rd, const float* __restrict__ b_rd, const float* __restrict__ U,
    short* __restrict__ Hb, short* __restrict__ Wall, float* __restrict__ ballf,
    short* __restrict__ Warcb, short* __restrict__ Ut)
{
  const int bx = blockIdx.x;
  if (bx < 2048) {
    for (long i = (long)bx * 256 + threadIdx.x; i < totV4; i += 2048L * 256) {
      if (i < nHv4) {
        f32x4 v = ((const f32x4*)H)[i];
        s16x4 o;
#pragma unroll
        for (int k = 0; k < 4; k++) o[k] = f2b(v[k]);
        ((s16x4*)Hb)[i] = o;
      } else if (i < nHv4 + nWv4) {
        long j = i - nHv4;
        long e = j * 4;
        const float* src;
        if (e < 512L * 768)        src = W_ah + e;
        else if (e < 1024L * 768)  src = W_ad + (e - 512L * 768);
        else if (e < 1152L * 768)  src = W_rh + (e - 1024L * 768);
        else                       src = W_rd + (e - 1152L * 768);
        f32x4 v = *(const f32x4*)src;
        s16x4 o;
#pragma unroll
        for (int k = 0; k < 4; k++) o[k] = f2b(v[k]);
        ((s16x4*)Wall)[j] = o;
      } else if (i < nHv4 + nWv4 + nAv4) {
        long j = i - nHv4 - nWv4;
        f32x4 v = ((const f32x4*)W_arc)[j];
        s16x4 o;
#pragma unroll
        for (int k = 0; k < 4; k++) o[k] = f2b(v[k]);
        ((s16x4*)Warcb)[j] = o;
      } else {
        long j = i - nHv4 - nWv4 - nAv4;
        long e = j * 4;
        const float* src;
        if (e < 512)       src = b_ah + e;
        else if (e < 1024) src = b_ad + (e - 512);
        else if (e < 1152) src = b_rh + (e - 1024);
        else               src = b_rd + (e - 1152);
        ((f32x4*)ballf)[j] = *(const f32x4*)src;
      }
    }
  } else {
    // Ut[c][e][d] = U[c][d][e], one 64x64 f32 tile per block via padded LDS
    __shared__ float tl[64][65];
    const int bt = bx - 2048;            // 0..147
    const int c = bt >> 2, t4 = bt & 3;
    const int d0 = (t4 & 1) * 64, e0 = (t4 >> 1) * 64;
    const float* Uc = U + (long)c * 16384;
    const int q = threadIdx.x & 15, rr = threadIdx.x >> 4;
#pragma unroll
    for (int it = 0; it < 4; it++) {
      int r = it * 16 + rr;              // d-row within tile
      f32x4 v = *(const f32x4*)&Uc[(long)(d0 + r) * 128 + e0 + q * 4];
#pragma unroll
      for (int k = 0; k < 4; k++) tl[r][q * 4 + k] = v[k];
    }
    __syncthreads();
#pragma unroll
    for (int it = 0; it < 4; it++) {
      int er = it * 16 + rr;             // e-row of output
      s16x4 o;
#pragma unroll
      for (int k = 0; k < 4; k++) o[k] = f2b(tl[q * 4 + k][er]);
      *(s16x4*)&Ut[(long)c * 16384 + (long)(e0 + er) * 128 + d0 + q * 4] = o;
    }
  }
}

// ---------------- 128x128 core: acc += A[128,K] * B[128,K]^T ----------------
DEVINL void gemm128_core(short* As, short* Bs,
                         const short* __restrict__ Ag, long lda,
                         const short* __restrict__ Bg, long ldb,
                         int K, f32x4 acc[4][4])
{
  const int t = threadIdx.x, lane = t & 63, w = t >> 6;
  const int wm = w >> 1, wn = w & 1, fr = lane & 15, hi = lane >> 4;
  const int srow = w * 8 + (lane >> 3);
  const int scol = (lane & 7) * 8;
  const short* Arow = Ag + (long)srow * lda + scol;
  const short* Brow = Bg + (long)srow * ldb + scol;

  for (int k0 = 0; k0 < K; k0 += 64) {
    __syncthreads();
#pragma unroll
    for (int i = 0; i < 4; i++) {
      gload16(Arow + (long)i * 32 * lda + k0, &As[(i * 4 + w) * 512]);
      gload16(Brow + (long)i * 32 * ldb + k0, &Bs[(i * 4 + w) * 512]);
    }
    __syncthreads();   // vmcnt(0) drained: global_load_lds completion is vmcnt-tracked
#pragma unroll
    for (int ks = 0; ks < 2; ks++) {
      bf16x8 a[4], b[4];
#pragma unroll
      for (int mf = 0; mf < 4; mf++)
        a[mf] = *(const bf16x8*)&As[(wm * 64 + mf * 16 + fr) * 64 + ks * 32 + hi * 8];
#pragma unroll
      for (int nf = 0; nf < 4; nf++)
        b[nf] = *(const bf16x8*)&Bs[(wn * 64 + nf * 16 + fr) * 64 + ks * 32 + hi * 8];
#pragma unroll
      for (int mf = 0; mf < 4; mf++)
#pragma unroll
        for (int nf = 0; nf < 4; nf++)
          acc[mf][nf] = __builtin_amdgcn_mfma_f32_16x16x32_bf16(a[mf], b[nf], acc[mf][nf], 0, 0, 0);
    }
  }
}

#define ZERO_ACC16 \
  f32x4 acc[4][4]; \
  for (int i = 0; i < 4; i++) for (int j = 0; j < 4; j++) for (int r = 0; r < 4; r++) acc[i][j][r] = 0.f;

// ---------------- projections: Proj = relu(Hb * Wall^T + ballf), bf16 out ----------------
__global__ __launch_bounds__(256) void k_proj(const short* __restrict__ Hb,
    const short* __restrict__ Wall, const float* __restrict__ ballf,
    short* __restrict__ Proj)
{
  __shared__ short As[128 * 64], Bs[128 * 64];
  const int tn = blockIdx.x, tm = blockIdx.y;
  ZERO_ACC16;
  gemm128_core(As, Bs, Hb + (long)tm * 128 * kDH, kDH, Wall + (long)tn * 128 * kDH, kDH, kDH, acc);
  const int lane = threadIdx.x & 63; const int w = threadIdx.x >> 6;
  const int wm = w >> 1, wn = w & 1, fr = lane & 15, hi = lane >> 4;
  for (int mf = 0; mf < 4; mf++) for (int nf = 0; nf < 4; nf++) for (int r = 0; r < 4; r++) {
    int row = tm * 128 + wm * 64 + mf * 16 + hi * 4 + r;
    int col = tn * 128 + wn * 64 + nf * 16 + fr;
    float v = acc[mf][nf][r] + ballf[col];
    v = v > 0.f ? v : 0.f;
    Proj[(long)row * kNP + col] = f2b(v);
  }
}

// ---------------- k_mid: T-tiles + Y-tiles + (rowterm|affine) in one launch ----------------
__global__ __launch_bounds__(256) void k_mid(const short* __restrict__ Proj,
    const short* __restrict__ Warcb, const short* __restrict__ Ut,
    const float* __restrict__ bias_arc, const float* __restrict__ W_rel,
    const float* __restrict__ bias_rel,
    short* __restrict__ T, short* __restrict__ Y,
    float* __restrict__ rowterm, float* __restrict__ affB)
{
  __shared__ short As[128 * 64], Bs[128 * 64];
  const int bx = blockIdx.x;
  const int t = threadIdx.x;

  if (bx < 1312) {
    const short* Ag; const short* Bg;
    long lda, ldb, ldd; int K, tm, tn; short* dst;
    if (bx < 128) {
      tn = bx & 3; tm = bx >> 2;
      Ag = Proj + (long)tm * 128 * kNP + 512; lda = kNP;
      Bg = Warcb + (long)tn * 128 * kDARC;    ldb = kDARC;
      K = kDARC; dst = T; ldd = kDARC;
    } else {
      int i = bx - 128; tn = i % 37; tm = i / 37;
      Ag = Proj + (long)tm * 128 * kNP + 1024; lda = kNP;
      Bg = Ut + (long)tn * 128 * kDREL;        ldb = kDREL;
      K = kDREL; dst = Y; ldd = kNY;
    }
    ZERO_ACC16;
    gemm128_core(As, Bs, Ag, lda, Bg, ldb, K, acc);
    const int lane = t & 63; const int w = t >> 6;
    const int wm = w >> 1, wn = w & 1, fr = lane & 15, hi = lane >> 4;
    for (int mf = 0; mf < 4; mf++) for (int nf = 0; nf < 4; nf++) for (int r = 0; r < 4; r++) {
      int row = tm * 128 + wm * 64 + mf * 16 + hi * 4 + r;
      int col = tn * 128 + wn * 64 + nf * 16 + fr;
      dst[(long)row * ldd + col] = f2b(acc[mf][nf][r]);
    }
  } else {
    __shared__ float h[4][256];
    const int base = (bx - 1312) * 8;
    const int w = t >> 6, lane = t & 63;
    for (int j = 0; j < 2; j++) {
      const int bl = base + w * 2 + j;
      const short* prow = Proj + (long)bl * kNP;
      float s = 0.f;
      bf16x8 hv = *(const bf16x8*)(prow + lane * 8);
#pragma unroll
      for (int i = 0; i < 8; i++) s += b2f(hv[i]) * bias_arc[lane * 8 + i];
      for (int off = 32; off; off >>= 1) s += __shfl_down(s, off, 64);
      if (lane == 0) rowterm[bl] = s;
      if (lane < 32) {
        bf16x8 v = *(const bf16x8*)(prow + 1024 + lane * 8);
        for (int i = 0; i < 8; i++) h[w][lane * 8 + i] = b2f(v[i]);
      }
      __syncthreads();
      if (lane < kC) {
        float sa = bias_rel[lane];
        const float* wr = W_rel + (long)lane * 256;
        for (int k = 0; k < 256; k++) sa += h[w][k] * wr[k];
        affB[(long)bl * kC + lane] = sa;
      }
      __syncthreads();
    }
  }
}

// ---------------- k_out: sarc (128x128 tiles) + srel v3b (R7-proven), dyn LDS ----------------
__global__ __launch_bounds__(256) void k_out(const short* __restrict__ T,
    const short* __restrict__ Proj, const float* __restrict__ rowterm,
    const short* __restrict__ Y, const float* __restrict__ affB,
    float* __restrict__ outArc, float* __restrict__ outRel)
{
  extern __shared__ short sm[];   // 32768 B
  const int t = threadIdx.x;
  const int lane = t & 63, w = t >> 6;
  const int fr = lane & 15, hi = lane >> 4;

  if (blockIdx.x < 128) {
    const int i = blockIdx.x;
    const int b = i >> 4, tm = (i >> 2) & 3, tn = i & 3;
    ZERO_ACC16;
    gemm128_core(sm, sm + 8192,
                 T + ((long)b * kL + tm * 128) * kDARC, kDARC,
                 Proj + ((long)b * kL + tn * 128) * kNP, kNP, kDARC, acc);
    const int wm = w >> 1, wn = w & 1;
    for (int mf = 0; mf < 4; mf++) for (int nf = 0; nf < 4; nf++) for (int r = 0; r < 4; r++) {
      int l = tm * 128 + wm * 64 + mf * 16 + hi * 4 + r;
      int m = tn * 128 + wn * 64 + nf * 16 + fr;
      outArc[((long)b * kL + l) * kL + m] = acc[mf][nf][r] + rowterm[(long)b * kL + l];
    }
  } else {
    const int idx = blockIdx.x - 128;
    const int h = idx & 1;
    const int l0 = ((idx >> 1) & 63) * 8;
    const int b = idx >> 7;
    const int mbase = h * 256;
    short* Bcur = sm;            // 48*136 = 6528 shorts
    short* Bnxt = sm + 6528;

    bf16x8 a[4][4];
    const short* Ab = Proj + ((long)b * kL + mbase + w * 64) * kNP + 1152;
#pragma unroll
    for (int mf = 0; mf < 4; mf++)
#pragma unroll
      for (int ks = 0; ks < 4; ks++)
        a[mf][ks] = *(const bf16x8*)(Ab + (long)(mf * 16 + fr) * kNP + ks * 32 + hi * 8);

    {
      const short* Yrow = Y + ((long)b * kL + l0) * kNY;
#pragma unroll
      for (int p = 0; p < 3; p++) {
        int i2 = p * 256 + t;
        if (i2 < 592)
          *(bf16x8*)&Bcur[(i2 >> 4) * 136 + (i2 & 15) * 8] = *(const bf16x8*)(Yrow + i2 * 8);
      }
    }
    lds_barrier();

    for (int il = 0; il < 8; il++) {
      const long bl = (long)b * kL + l0 + il;

      bf16x8 n0, n1, n2;
      if (il < 7) {
        const short* Yn = Y + (bl + 1) * kNY;
        n0 = *(const bf16x8*)(Yn + t * 8);
        n1 = *(const bf16x8*)(Yn + (long)(256 + t) * 8);
        if (t < 80) n2 = *(const bf16x8*)(Yn + (long)(512 + t) * 8);
      }

      f32x4 acc[4][3];
#pragma unroll
      for (int mf = 0; mf < 4; mf++)
#pragma unroll
        for (int nf = 0; nf < 3; nf++)
          for (int r = 0; r < 4; r++) acc[mf][nf][r] = 0.f;

#pragma unroll
      for (int ks = 0; ks < 4; ks++) {
        bf16x8 bfr[3];
#pragma unroll
        for (int nf = 0; nf < 3; nf++)
          bfr[nf] = *(const bf16x8*)&Bcur[(nf * 16 + fr) * 136 + ks * 32 + hi * 8];
#pragma unroll
        for (int mf = 0; mf < 4; mf++)
#pragma unroll
          for (int nf = 0; nf < 3; nf++)
            acc[mf][nf] = __builtin_amdgcn_mfma_f32_16x16x32_bf16(a[mf][ks], bfr[nf], acc[mf][nf], 0, 0, 0);
      }
      lds_barrier();   // all waves done reading Bcur; its space becomes scratch

      float aff[3];
#pragma unroll
      for (int nf = 0; nf < 3; nf++) {
        int c = nf * 16 + fr;
        aff[nf] = (c < kC) ? affB[bl * kC + c] : 0.f;
      }

      float* scr = (float*)Bcur + w * 592;
#pragma unroll
      for (int mf = 0; mf < 4; mf++) {
#pragma unroll
        for (int nf = 0; nf < 3; nf++) {
          int c = nf * 16 + fr;
          if (c < kC) {
#pragma unroll
            for (int r = 0; r < 4; r++)
              scr[(hi * 4 + r) * kC + c] = acc[mf][nf][r] + aff[nf];
          }
        }
        float* gb = outRel + (bl * kL + mbase + w * 64 + mf * 16) * kC;
#pragma unroll
        for (int p = 0; p < 3; p++) {
          int i4 = p * 64 + lane;
          if (i4 < 148) {
            f32x4 v = *(f32x4*)&scr[i4 * 4];
            *(f32x4*)&gb[i4 * 4] = v;
          }
        }
      }

      if (il < 7) {
        *(bf16x8*)&Bnxt[(t >> 4) * 136 + (t & 15) * 8] = n0;
        {
          int i2 = 256 + t;
          *(bf16x8*)&Bnxt[(i2 >> 4) * 136 + (i2 & 15) * 8] = n1;
        }
        if (t < 80) {
          int i2 = 512 + t;
          *(bf16x8*)&Bnxt[(i2 >> 4) * 136 + (i2 & 15) * 8] = n2;
        }
        lds_barrier();
        short* tmp = Bcur; Bcur = Bnxt; Bnxt = tmp;
      }
    }
  }
}

extern "C" void kernel_launch(void* const* d_in, const int* in_sizes, int n_in,
                              void* d_out, int out_size, void* d_ws, size_t ws_size,
                              hipStream_t stream) {
  const float* H        = (const float*)d_in[0];
  const float* W_ah     = (const float*)d_in[1];
  const float* b_ah     = (const float*)d_in[2];
  const float* W_ad     = (const float*)d_in[3];
  const float* b_ad     = (const float*)d_in[4];
  const float* W_arc    = (const float*)d_in[5];
  const float* bias_arc = (const float*)d_in[6];
  const float* W_rh     = (const float*)d_in[7];
  const float* b_rh     = (const float*)d_in[8];
  const float* W_rd     = (const float*)d_in[9];
  const float* b_rd     = (const float*)d_in[10];
  const float* U_rel    = (const float*)d_in[11];
  const float* W_rel    = (const float*)d_in[12];
  const float* bias_rel = (const float*)d_in[13];

  size_t off = 0;
  auto take = [&](size_t nbytes) -> void* {
    void* p = (char*)d_ws + off;
    off += (nbytes + 255) & ~(size_t)255;
    return p;
  };
  short* Hb      = (short*)take(nHB * 2);
  short* Wall    = (short*)take(nWALL * 2);
  float* ballf   = (float*)take(nBALL * 4);
  short* Warcb   = (short*)take(nWARC * 2);
  short* Ut      = (short*)take(nUT * 2);
  short* Proj    = (short*)take((long)kBL * kNP * 2);
  short* T       = (short*)take((long)kBL * kDARC * 2);
  short* Y       = (short*)take((long)kBL * kNY * 2);
  float* rowterm = (float*)take((long)kBL * 4);
  float* affB    = (float*)take((long)kBL * kC * 4);
  if (off > ws_size) return;

  float* outArc = (float*)d_out;
  float* outRel = outArc + (long)kB * kL * kL;

  k_convert<<<dim3(2048 + 148), dim3(256), 0, stream>>>(H, W_ah, b_ah, W_ad, b_ad, W_arc,
                                                        W_rh, b_rh, W_rd, b_rd, U_rel,
                                                        Hb, Wall, ballf, Warcb, Ut);
  k_proj<<<dim3(kNP / 128, kBL / 128), dim3(256), 0, stream>>>(Hb, Wall, ballf, Proj);
  k_mid<<<dim3(1824), dim3(256), 0, stream>>>(Proj, Warcb, Ut, bias_arc, W_rel, bias_rel,
                                              T, Y, rowterm, affB);
  k_out<<<dim3(1152), dim3(256), 32768, stream>>>(T, Proj, rowterm, Y, affB, outArc, outRel);
}